// Round 11
// baseline (4429.723 us; speedup 1.0000x reference)
//
#include <hip/hip_runtime.h>
#include <math.h>

#define BN_EPS 1e-5f

typedef _Float16 f16x8 __attribute__((ext_vector_type(8)));
typedef _Float16 f16x4 __attribute__((ext_vector_type(4)));
typedef _Float16 f16x2 __attribute__((ext_vector_type(2)));
typedef unsigned short u16x8 __attribute__((ext_vector_type(8)));
typedef float f32x4 __attribute__((ext_vector_type(4)));
typedef float f32x16 __attribute__((ext_vector_type(16)));

// ---------------------------------------------------------------------------
// Workspace (float offsets):
//  We     @ 0        (5376)    f32 encoder weight (BN folded)
//  be     @ 8192     (64)
//  W2     @ 12288    (65536)   lin_w repeat-16 folded
//  A      @ 81920    (262144)  x-path i,f matrix fp32 [go][c][p]
//  Abias  @ 344064   (4096)
//  WeF    @ 348160   (6144 halves = 3072 fl)  stage-1 A-frags
//  Apk    @ 352256   (262144 halves = 131072 fl) stage-2 A-frags
//  Wcv    @ 483328   (147456 halves = 73728 fl)  conv A-frags
//  h16    @ 557056   (4194304 halves) h state [b][p][ch] f16
//  cstate @ 2654208  (4194304 fl) c state, [block][p][cell] layout
//  sixf   @ 6848512  (67108864 halves) layout [b][trel][slot][ch][p]
//  end 40402944 fl = 161.6 MB
//
// LEDGER (hard-won):
//  - recur8 K-loop must not grow live registers (r3/r4/r9 spills).
//  - recur8 true reg use ~170/wave (wr 108 + acc 16 + addr) x 12 waves
//    = full 2048 pool -> 1 block/CU is a REGISTER cap, not LDS (r9).
//  - never force waves-per-EU above natural allocation (r8: VGPR 40, 1.1 GB spill).
//  - r5 recur8 structure is the schedule optimum; r6/r7 fusion variants lose.
//  - xgate r5 block mapping (gq-based slot) beats balanced remap (r10, -7 us).
//  - recur8 critical path = update's TRANS ops (4 exp + 4 rcp/px), not MFMA.
// ---------------------------------------------------------------------------

__global__ void prep_enc_w(const float* __restrict__ conv1d_w,
                           const float* __restrict__ conv1d_b,
                           const float* __restrict__ gamma,
                           const float* __restrict__ beta,
                           const float* __restrict__ mean,
                           const float* __restrict__ var,
                           float* __restrict__ We, float* __restrict__ be) {
  int tid = blockIdx.x * blockDim.x + threadIdx.x;
  if (tid < 5376) {
    int c = tid / 84, f = tid % 84;
    float s = gamma[c] * rsqrtf(var[c] + BN_EPS);
    We[c * 84 + f] = s * conv1d_w[c * 252 + f * 3 + 1];
    if (f == 0) be[c] = s * conv1d_b[c] + (beta[c] - mean[c] * s);
  }
}

// stage-1 A-frags for encoder MFMA: WeF[(ct*3+kch)*64+lane][8], K padded 84->96
__global__ void prep_wef(const float* __restrict__ We, _Float16* __restrict__ WeF) {
  int tid = blockIdx.x * blockDim.x + threadIdx.x;  // 6144
  if (tid >= 6144) return;
  int j = tid & 7, lane = (tid >> 3) & 63, kch = (tid >> 9) % 3, ct = tid / 1536;
  int c = ct * 16 + (lane & 15);
  int k = kch * 32 + (lane >> 4) * 8 + j;
  WeF[tid] = (k < 84) ? (_Float16)We[c * 84 + k] : (_Float16)0.f;
}

__global__ void prep_w2(const float* __restrict__ lin_w, float* __restrict__ W2) {
  int tid = blockIdx.x * blockDim.x + threadIdx.x;  // 65536
  int o2 = tid >> 6, c = tid & 63;
  float s = 0.f;
#pragma unroll
  for (int j = 0; j < 16; ++j) s += lin_w[o2 * 1024 + c * 16 + j];
  W2[o2 * 64 + c] = s;
}

__global__ void prep_A(const float* __restrict__ cell_w,
                       const float* __restrict__ cell_b,
                       const float* __restrict__ lin_b,
                       const float* __restrict__ W2,
                       float* __restrict__ A, float* __restrict__ Abias) {
  int tid = blockIdx.x * blockDim.x + threadIdx.x;  // 262144
  int go = tid >> 10;
  int c = (tid >> 4) & 63;
  int p = tid & 15;
  int y = p >> 2, x = p & 3;
  int kn = (go >= 128) ? 16 : 48;
  int xb = (go >= 128) ? 48 : 0;
  float a = 0.f;
  for (int k = 0; k < kn; ++k)
    for (int dy = 0; dy < 3; ++dy) {
      int yy = y + dy - 1;
      if (yy < 0 || yy > 3) continue;
      for (int dx = 0; dx < 3; ++dx) {
        int xx = x + dx - 1;
        if (xx < 0 || xx > 3) continue;
        a += cell_w[((go * 48 + k) * 3 + dy) * 3 + dx] *
             W2[((xb + k) * 16 + yy * 4 + xx) * 64 + c];
      }
    }
  A[(go * 64 + c) * 16 + p] = a;
  if (c == 0) {
    float bs = cell_b[go];
    for (int k = 0; k < kn; ++k)
      for (int dy = 0; dy < 3; ++dy) {
        int yy = y + dy - 1;
        if (yy < 0 || yy > 3) continue;
        for (int dx = 0; dx < 3; ++dx) {
          int xx = x + dx - 1;
          if (xx < 0 || xx > 3) continue;
          bs += cell_w[((go * 48 + k) * 3 + dy) * 3 + dx] *
                lin_b[(xb + k) * 16 + yy * 4 + xx];
        }
      }
    Abias[go * 16 + p] = bs;
  }
}

// A fp32 [go][c][p] -> 16x16x32 A-frags: Apk[go][kch][lane][8]
__global__ void pack_a16(const float* __restrict__ A, _Float16* __restrict__ Apk) {
  int tid = blockIdx.x * blockDim.x + threadIdx.x;  // 262144
  int j = tid & 7, lane = (tid >> 3) & 63, kch = (tid >> 9) & 1, go = tid >> 10;
  int p = lane & 15;
  int c = kch * 32 + (lane >> 4) * 8 + j;
  Apk[tid] = (_Float16)A[(go * 64 + c) * 16 + p];
}

// cell_w -> 32x32x16 conv A-frags: [f 2kch | o 3kch | g 3kch][(kch*9+tap)*4+m][lane][8]
__global__ void pack_wcv(const float* __restrict__ cell_w, _Float16* __restrict__ Wcv) {
  int tid = blockIdx.x * blockDim.x + threadIdx.x;  // 147456
  int j = tid & 7, lane = (tid >> 3) & 63, m = (tid >> 9) & 3, tmk = tid >> 11;
  int co = m * 32 + (lane & 31);
  int khi = (lane >> 5) * 8 + j;
  float v;
  if (tmk < 18) {
    int kch = tmk / 9, tap = tmk % 9;
    v = cell_w[((size_t)(128 + co) * 48 + 16 + kch * 16 + khi) * 9 + tap];
  } else if (tmk < 45) {
    int r = tmk - 18; int kch = r / 9, tap = r % 9;
    v = cell_w[((size_t)(256 + co) * 48 + kch * 16 + khi) * 9 + tap];
  } else {
    int r = tmk - 45; int kch = r / 9, tap = r % 9;
    v = cell_w[((size_t)(384 + co) * 48 + kch * 16 + khi) * 9 + tap];
  }
  Wcv[tid] = (_Float16)v;
}

__device__ __forceinline__ float sigm(float v) {
  return __fdividef(1.f, 1.f + __expf(-v));
}
__device__ __forceinline__ float tanh_fast(float v) {
  return 1.f - __fdividef(2.f, __expf(2.f * v) + 1.f);
}

// ---------------------------------------------------------------------------
// xgate: round-5 version verbatim (verified best: ~52 us/dispatch).
// ---------------------------------------------------------------------------
__global__ __launch_bounds__(256, 3) void xgate_kernel(
    const float* __restrict__ x, const _Float16* __restrict__ WeF,
    const float* __restrict__ be, const _Float16* __restrict__ Apk,
    const float* __restrict__ Abias, unsigned short* __restrict__ sixf, int tc) {
  __shared__ __align__(16) _Float16 x16[128 * 104];     // 26624 B
  __shared__ __align__(16) _Float16 enc_s[128 * 72];    // 18432 B
  __shared__ __align__(16) unsigned char Tt[4 * 2304];  // 9216 B, wave-private
  int tid = threadIdx.x, lane = tid & 63, w = tid >> 6;
  int gq = blockIdx.x >> 7, cq = blockIdx.x & 127;
  int n = lane & 15, kgrp = lane >> 4;

  {
    int r = tid >> 1, half = tid & 1;
    int b = cq * 16 + (r >> 3), t = tc * 8 + (r & 7);
    const float* rowp = x + ((size_t)b * 128 + t) * 84;
#pragma unroll
    for (int j = 0; j < 11; ++j) {
      int q = half + 2 * j;
      if (q < 21) {
        float4 v = *(const float4*)(rowp + q * 4);
        f16x4 h;
        h[0] = (_Float16)v.x; h[1] = (_Float16)v.y;
        h[2] = (_Float16)v.z; h[3] = (_Float16)v.w;
        *(f16x4*)(&x16[r * 104 + q * 4]) = h;
      }
    }
    for (int i = tid; i < 4096; i += 256) {
      int rr = i >> 5, k = i & 31;
      if (k < 20) x16[rr * 104 + 84 + k] = (_Float16)0.f;
    }
  }
  __syncthreads();

  for (int ct4 = 0; ct4 < 8; ++ct4) {
    f32x4 acc = *(const f32x4*)(be + w * 16 + kgrp * 4);
#pragma unroll
    for (int kch = 0; kch < 3; ++kch)
      acc = __builtin_amdgcn_mfma_f32_16x16x32_f16(
          *(const f16x8*)(WeF + ((w * 3 + kch) * 64 + lane) * 8),
          *(const f16x8*)(&x16[(ct4 * 16 + n) * 104 + kch * 32 + kgrp * 8]),
          acc, 0, 0, 0);
#pragma unroll
    for (int r = 0; r < 4; ++r)
      enc_s[(ct4 * 16 + n) * 72 + w * 16 + kgrp * 4 + r] =
          (_Float16)fmaxf(acc[r], 0.f);
  }
  __syncthreads();

  int slotB = gq >> 1;
  int chbase = (gq & 1) * 64 + w * 16;
  unsigned char* Tw = Tt + w * 2304;
  int fn = lane >> 2;
  for (int ct4 = 0; ct4 < 8; ++ct4) {
    int ccl = ct4 * 16 + n;
    int fb = cq * 16 + ct4 * 2 + (fn >> 3), ftr = fn & 7;
    size_t grow =
        (((size_t)fb * 8 + ftr) * 2 + slotB) * 2048 + (size_t)chbase * 16;
    for (int gb = 0; gb < 4; ++gb) {
#pragma unroll
      for (int gi = 0; gi < 4; ++gi) {
        int gol = gb * 4 + gi;
        int go = gq * 64 + w * 16 + gol;
        f32x4 acc = *(const f32x4*)(Abias + go * 16 + kgrp * 4);
        acc = __builtin_amdgcn_mfma_f32_16x16x32_f16(
            *(const f16x8*)(Apk + (size_t)go * 1024 + lane * 8),
            *(const f16x8*)(&enc_s[ccl * 72 + kgrp * 8]), acc, 0, 0, 0);
        acc = __builtin_amdgcn_mfma_f32_16x16x32_f16(
            *(const f16x8*)(Apk + (size_t)go * 1024 + 512 + lane * 8),
            *(const f16x8*)(&enc_s[ccl * 72 + 32 + kgrp * 8]), acc, 0, 0, 0);
        unsigned char* tdst = Tw + n * 144 + gi * 32 + kgrp * 8;
        if (gq < 2) {
#pragma unroll
          for (int rp = 0; rp < 2; ++rp) {
            unsigned lo = (unsigned)(sigm(acc[rp * 2]) * 65535.f + 0.5f);
            unsigned hi = (unsigned)(sigm(acc[rp * 2 + 1]) * 65535.f + 0.5f);
            *(unsigned*)(tdst + rp * 4) = lo | (hi << 16);
          }
        } else {
#pragma unroll
          for (int rp = 0; rp < 2; ++rp) {
            f16x2 pv = {(_Float16)acc[rp * 2], (_Float16)acc[rp * 2 + 1]};
            *(f16x2*)(tdst + rp * 4) = pv;
          }
        }
      }
      asm volatile("s_waitcnt lgkmcnt(0)" ::: "memory");
      __builtin_amdgcn_sched_barrier(0);
#pragma unroll
      for (int j = 0; j < 2; ++j) {
        int chunk = (lane & 3) + 4 * j;
        f16x8 v = *(const f16x8*)(Tw + fn * 144 + chunk * 16);
        *(f16x8*)(sixf + grow + (size_t)gb * 64 + (size_t)chunk * 8) = v;
      }
      asm volatile("s_waitcnt lgkmcnt(0)" ::: "memory");
      __builtin_amdgcn_sched_barrier(0);
    }
  }
}

// ---------------------------------------------------------------------------
// recur8: r5 structure verbatim; round-11 change is INSIDE cell_update only:
// shared-rcp activation math. Per pixel, trans ops 8 -> 6:
//   cv = [c*(E2+1) + si*(E2-1)*(1+E1)] * rcp((1+E1)*(E2+1))
//   hn = (E4-1) * rcp((1+E3)*(E4+1))
// with exp args clamped at 40 (e^40=2.4e17; products <= 5.5e34 < f32 max)
// to avoid the inf/inf->NaN corner the old per-op __fdividef form dodged.
// LDS map: h_pad [8b][17q][128ch] @0 (36992) | c [16p][1024cell] @36992
//          (65536) | G 3x[128ch rows 144B][4bl][16p] f16 @102528 (55296)
//          total 157824
// ---------------------------------------------------------------------------
#define HPB 4624
#define HPQ 272
#define ZQ 4352
#define COFF 36992
#define GOFF 102528
#define GSZ 18432
#define LDSZ 157824

__device__ __forceinline__ void cell_update(
    unsigned char* lds, const unsigned short* __restrict__ sixf_b,
    _Float16* __restrict__ h16_b, int ch, int bl, int hf, int t,
    float cbo, float cbg, bool lastT) {
  int b = hf * 4 + bl;
  int cell = hf * 512 + ch * 4 + bl;
  const unsigned short* sp = sixf_b + ((size_t)b * 8 + t) * 4096 + ch * 16;
  u16x8 s0 = *(const u16x8*)(sp);
  u16x8 s1 = *(const u16x8*)(sp + 8);
  f16x8 x0 = *(const f16x8*)(sp + 2048);
  f16x8 x1 = *(const f16x8*)(sp + 2056);
  const _Float16* Gf = (const _Float16*)(lds + GOFF + 0 * GSZ + ch * 144 + bl * 32);
  const _Float16* Go = (const _Float16*)(lds + GOFF + 1 * GSZ + ch * 144 + bl * 32);
  const _Float16* Gg = (const _Float16*)(lds + GOFF + 2 * GSZ + ch * 144 + bl * 32);
  float* cp = (float*)(lds + COFF) + cell;
#pragma unroll
  for (int h8 = 0; h8 < 2; ++h8) {
    u16x8 s = h8 ? s1 : s0;
    f16x8 xv = h8 ? x1 : x0;
    f16x8 gfv = *(const f16x8*)(Gf + h8 * 8);
    f16x8 gov = *(const f16x8*)(Go + h8 * 8);
    f16x8 ggv = *(const f16x8*)(Gg + h8 * 8);
#pragma unroll
    for (int j = 0; j < 8; ++j) {
      int p = h8 * 8 + j;
      float si = (float)s[j] * (1.f / 65535.f);
      float u = (float)xv[j] + (float)gfv[j];   // f-gate preact
      float v = cbg + (float)ggv[j];            // g preact
      float E1 = __expf(fminf(-u, 40.f));
      float E2 = __expf(fminf(2.f * v, 40.f));
      float a1 = 1.f + E1, a2 = E2 + 1.f;
      float cold = cp[p * 1024];
      float cv = (cold * a2 + si * (E2 - 1.f) * a1) *
                 __builtin_amdgcn_rcpf(a1 * a2);
      cp[p * 1024] = cv;
      float wo = cbo + (float)gov[j];           // o preact
      float E3 = __expf(fminf(-wo, 40.f));
      float E4 = __expf(fminf(2.f * cv, 40.f));
      float hn = (E4 - 1.f) *
                 __builtin_amdgcn_rcpf((1.f + E3) * (E4 + 1.f));
      *(_Float16*)(lds + b * HPB + p * HPQ + ch * 2) = (_Float16)hn;
      if (lastT) h16_b[((size_t)b * 16 + p) * 128 + ch] = (_Float16)hn;
    }
  }
}

template <int GATE>
__device__ __forceinline__ void role_loop(
    unsigned char* lds, const _Float16* __restrict__ Wg,
    const unsigned short* __restrict__ sixf_b,
    _Float16* __restrict__ h16_b, const float* __restrict__ cell_b,
    int m, int lane, int tid, const unsigned* tapbase, unsigned gwbase) {
  constexpr int NKCH = (GATE == 0) ? 2 : 3;
  constexpr unsigned CIOFF = (GATE == 0) ? 0u : (GATE == 1 ? 64u : 160u);
  f16x8 wr[NKCH * 9];
#pragma unroll
  for (int fi = 0; fi < NKCH * 9; ++fi)
    wr[fi] = *(const f16x8*)(Wg + (size_t)(fi * 4 + m) * 512 + (lane << 3));

  int idx = (GATE == 2) ? (tid - 256) : tid;
  int ch = idx >> 2, bl = idx & 3;
  constexpr bool own0 = (GATE != 2), own1 = (GATE != 1);
  float cbo = cell_b[256 + ch], cbg = cell_b[384 + ch];

  for (int t = 0; t < 8; ++t) {
#pragma unroll
    for (int hf = 0; hf < 2; ++hf) {
#pragma unroll
      for (int nt = 0; nt < 2; ++nt) {
        unsigned bofs = (unsigned)(hf * 4 + nt * 2) * HPB;
        f32x16 acc = {};
#pragma unroll
        for (int kch = 0; kch < NKCH; ++kch)
#pragma unroll
          for (int tap = 0; tap < 9; ++tap)
            acc = __builtin_amdgcn_mfma_f32_32x32x16_f16(
                wr[kch * 9 + tap],
                *(const f16x8*)(lds + tapbase[tap] + bofs + CIOFF +
                                (unsigned)kch * 32),
                acc, 0, 0, 0);
#pragma unroll
        for (int r = 0; r < 16; ++r) {
          unsigned co_l = (unsigned)((r & 3) + 8 * (r >> 2));
          *(_Float16*)(lds + gwbase + (unsigned)GATE * GSZ + co_l * 144u +
                       (unsigned)nt * 64u) = (_Float16)acc[r];
        }
      }
      __syncthreads();
      if (hf == 0) {
        if (own0) cell_update(lds, sixf_b, h16_b, ch, bl, 0, t, cbo, cbg, t == 7);
      } else {
        if (own1) cell_update(lds, sixf_b, h16_b, ch, bl, 1, t, cbo, cbg, t == 7);
      }
      __syncthreads();
    }
  }
}

__global__ __launch_bounds__(768, 3) void recur8_kernel(
    const unsigned short* __restrict__ sixf, const _Float16* __restrict__ Wcv,
    const float* __restrict__ cell_b, _Float16* __restrict__ h16,
    float* __restrict__ cstate) {
  __shared__ __align__(16) unsigned char lds[LDSZ];
  int tid = threadIdx.x, lane = tid & 63, w = tid >> 6;
  int gate = w >> 2, m = w & 3;

  _Float16* h16_b = h16 + (size_t)blockIdx.x * 16384;
  for (int i = tid; i < 16384; i += 768) {
    int bl8 = i >> 11, q = (i >> 7) & 15, chh = i & 127;
    *(_Float16*)(lds + bl8 * HPB + q * HPQ + chh * 2) = h16_b[i];
  }
  for (int i = tid; i < 1024; i += 768) {
    int bl8 = i >> 7, chh = i & 127;
    *(_Float16*)(lds + bl8 * HPB + ZQ + chh * 2) = (_Float16)0.f;
  }
  float* cl = (float*)(lds + COFF);
  float* cst_b = cstate + (size_t)blockIdx.x * 16384;
  for (int i = tid; i < 16384; i += 768) cl[i] = cst_b[i];

  int col = lane & 31, khalf = lane >> 5, b_lo = col >> 4, p_c = col & 15;
  int yc = p_c >> 2, xc = p_c & 3;
  unsigned tapbase[9];
#pragma unroll
  for (int dy = 0; dy < 3; ++dy)
#pragma unroll
    for (int dx = 0; dx < 3; ++dx) {
      int qy = yc + dy - 1, qx = xc + dx - 1;
      bool valid = (qy >= 0 && qy < 4 && qx >= 0 && qx < 4);
      tapbase[dy * 3 + dx] =
          (valid ? (unsigned)((qy * 4 + qx) * HPQ) : (unsigned)ZQ) +
          (unsigned)(b_lo * HPB + khalf * 16);
    }
  unsigned gwbase = (unsigned)GOFF + (unsigned)((m * 32 + khalf * 4) * 144) +
                    (unsigned)(b_lo * 32 + p_c * 2);
  __syncthreads();

  const unsigned short* sixf_b = sixf + (size_t)blockIdx.x * 262144;
  if (gate == 0)
    role_loop<0>(lds, Wcv, sixf_b, h16_b, cell_b, m, lane, tid, tapbase, gwbase);
  else if (gate == 1)
    role_loop<1>(lds, Wcv + 36864, sixf_b, h16_b, cell_b, m, lane, tid, tapbase, gwbase);
  else
    role_loop<2>(lds, Wcv + 92160, sixf_b, h16_b, cell_b, m, lane, tid, tapbase, gwbase);

  // role_loop ends with a trailing __syncthreads(): all c updates visible.
  for (int i = tid; i < 16384; i += 768) cst_b[i] = cl[i];
}

__global__ __launch_bounds__(128) void cls_kernel(
    const _Float16* __restrict__ h16, const float* __restrict__ w1,
    const float* __restrict__ b1, const float* __restrict__ w2,
    const float* __restrict__ b2, float* __restrict__ out) {
  __shared__ __align__(16) float feat[8 * 2064];
  __shared__ float hid[8 * 128];
  int b0 = blockIdx.x * 8;
  for (int i = threadIdx.x; i < 16384; i += 128) {
    int bl = i >> 11, r = i & 2047, p = r >> 7, chh = r & 127;
    feat[bl * 2064 + chh * 16 + p] = (float)h16[(size_t)b0 * 2048 + i];
  }
  __syncthreads();
  int ch = threadIdx.x;
  float acc[8];
#pragma unroll
  for (int b = 0; b < 8; ++b) acc[b] = b1[ch];
  const float4* wr = (const float4*)(w1 + (size_t)ch * 2048);
  for (int k4 = 0; k4 < 512; ++k4) {
    float4 wv = wr[k4];
#pragma unroll
    for (int b = 0; b < 8; ++b) {
      float4 f = *(const float4*)(&feat[b * 2064 + k4 * 4]);
      acc[b] += wv.x * f.x + wv.y * f.y + wv.z * f.z + wv.w * f.w;
    }
  }
#pragma unroll
  for (int b = 0; b < 8; ++b) hid[b * 128 + ch] = fmaxf(acc[b], 0.f);
  __syncthreads();
  if (threadIdx.x < 16) {
    int b = threadIdx.x >> 1, o = threadIdx.x & 1;
    float s = b2[o];
    for (int k = 0; k < 128; ++k) s += hid[b * 128 + k] * w2[o * 128 + k];
    out[(size_t)(b0 + b) * 2 + o] = s;
  }
}

extern "C" void kernel_launch(void* const* d_in, const int* in_sizes, int n_in,
                              void* d_out, int out_size, void* d_ws, size_t ws_size,
                              hipStream_t stream) {
  const float* x        = (const float*)d_in[0];
  const float* conv1d_w = (const float*)d_in[1];
  const float* conv1d_b = (const float*)d_in[2];
  const float* bn_gamma = (const float*)d_in[3];
  const float* bn_beta  = (const float*)d_in[4];
  const float* bn_mean  = (const float*)d_in[5];
  const float* bn_var   = (const float*)d_in[6];
  const float* lin_w    = (const float*)d_in[7];
  const float* lin_b    = (const float*)d_in[8];
  const float* cell_w   = (const float*)d_in[9];
  const float* cell_b   = (const float*)d_in[10];
  const float* cls1_w   = (const float*)d_in[11];
  const float* cls1_b   = (const float*)d_in[12];
  const float* cls2_w   = (const float*)d_in[13];
  const float* cls2_b   = (const float*)d_in[14];

  float* ws = (float*)d_ws;
  float* We    = ws + 0;
  float* be    = ws + 8192;
  float* W2    = ws + 12288;
  float* A     = ws + 81920;
  float* Abias = ws + 344064;
  _Float16* WeF = (_Float16*)(ws + 348160);
  _Float16* Apk = (_Float16*)(ws + 352256);
  _Float16* Wcv = (_Float16*)(ws + 483328);
  _Float16* h16 = (_Float16*)(ws + 557056);
  float* cstate = ws + 2654208;
  unsigned short* sixf = (unsigned short*)(ws + 6848512);
  float* out = (float*)d_out;

  prep_enc_w<<<21, 256, 0, stream>>>(conv1d_w, conv1d_b, bn_gamma, bn_beta,
                                     bn_mean, bn_var, We, be);
  prep_wef<<<24, 256, 0, stream>>>(We, WeF);
  prep_w2<<<256, 256, 0, stream>>>(lin_w, W2);
  prep_A<<<1024, 256, 0, stream>>>(cell_w, cell_b, lin_b, W2, A, Abias);
  pack_a16<<<1024, 256, 0, stream>>>(A, Apk);
  pack_wcv<<<576, 256, 0, stream>>>(cell_w, Wcv);
  hipMemsetAsync(h16, 0, 8388608, stream);
  hipMemsetAsync(cstate, 0, 16777216, stream);
  for (int tc = 0; tc < 16; ++tc) {
    xgate_kernel<<<512, 256, 0, stream>>>(x, WeF, be, Apk, Abias, sixf, tc);
    recur8_kernel<<<256, 768, 0, stream>>>(sixf, Wcv, cell_b, h16, cstate);
  }
  cls_kernel<<<256, 128, 0, stream>>>(h16, cls1_w, cls1_b, cls2_w, cls2_b, out);
}

// Round 12
// 3510.416 us; speedup vs baseline: 1.2619x; 1.2619x over previous
//
#include <hip/hip_runtime.h>
#include <math.h>

#define BN_EPS 1e-5f

typedef _Float16 f16x8 __attribute__((ext_vector_type(8)));
typedef _Float16 f16x4 __attribute__((ext_vector_type(4)));
typedef _Float16 f16x2 __attribute__((ext_vector_type(2)));
typedef unsigned short u16x8 __attribute__((ext_vector_type(8)));
typedef float f32x4 __attribute__((ext_vector_type(4)));
typedef float f32x16 __attribute__((ext_vector_type(16)));

// ---------------------------------------------------------------------------
// Workspace (float offsets):
//  We     @ 0        (5376)    f32 encoder weight (BN folded)
//  be     @ 8192     (64)
//  W2     @ 12288    (65536)   lin_w repeat-16 folded
//  A      @ 81920    (262144)  x-path i,f matrix fp32 [go][c][p]
//  Abias  @ 344064   (4096)
//  WeF    @ 348160   (6144 halves = 3072 fl)  stage-1 A-frags
//  Apk    @ 352256   (262144 halves = 131072 fl) stage-2 A-frags
//  Wcv    @ 483328   (147456 halves = 73728 fl)  conv A-frags
//  h16    @ 557056   (4194304 halves) h state [b][p][ch] f16
//  cstate @ 2654208  (4194304 fl) c state, [block][p][cell] layout
//  sixf   @ 6848512  (67108864 halves) layout [b][trel][slot][ch][p]
//  end 40402944 fl = 161.6 MB
//
// LEDGER (hard-won; r5 config below is the verified optimum, 3515 us):
//  - recur8 K-loop must not grow live registers (r3/r4/r9 spills).
//  - recur8 UPDATE loop is also register-knife-edge: widening the transient
//    live set (r11 shared-rcp math) spills too. Keep short per-op chains.
//  - recur8 true reg use ~170/wave (wr 108 + acc 16 + addr) x 12 waves
//    = full 2048 pool -> 1 block/CU is a REGISTER cap, not LDS (r9).
//  - never force waves-per-EU above natural allocation (r8: VGPR 40, 1.1 GB spill).
//  - r5 recur8 serial schedule beats fusion (r6: scalar-LDS VALU, r7: c-layout
//    bank conflicts); halved tile gains nothing (register cap, r9).
//  - xgate r5 block mapping (gq-based slot) beats balanced remap (r10, -7 us).
// ---------------------------------------------------------------------------

__global__ void prep_enc_w(const float* __restrict__ conv1d_w,
                           const float* __restrict__ conv1d_b,
                           const float* __restrict__ gamma,
                           const float* __restrict__ beta,
                           const float* __restrict__ mean,
                           const float* __restrict__ var,
                           float* __restrict__ We, float* __restrict__ be) {
  int tid = blockIdx.x * blockDim.x + threadIdx.x;
  if (tid < 5376) {
    int c = tid / 84, f = tid % 84;
    float s = gamma[c] * rsqrtf(var[c] + BN_EPS);
    We[c * 84 + f] = s * conv1d_w[c * 252 + f * 3 + 1];
    if (f == 0) be[c] = s * conv1d_b[c] + (beta[c] - mean[c] * s);
  }
}

// stage-1 A-frags for encoder MFMA: WeF[(ct*3+kch)*64+lane][8], K padded 84->96
__global__ void prep_wef(const float* __restrict__ We, _Float16* __restrict__ WeF) {
  int tid = blockIdx.x * blockDim.x + threadIdx.x;  // 6144
  if (tid >= 6144) return;
  int j = tid & 7, lane = (tid >> 3) & 63, kch = (tid >> 9) % 3, ct = tid / 1536;
  int c = ct * 16 + (lane & 15);
  int k = kch * 32 + (lane >> 4) * 8 + j;
  WeF[tid] = (k < 84) ? (_Float16)We[c * 84 + k] : (_Float16)0.f;
}

__global__ void prep_w2(const float* __restrict__ lin_w, float* __restrict__ W2) {
  int tid = blockIdx.x * blockDim.x + threadIdx.x;  // 65536
  int o2 = tid >> 6, c = tid & 63;
  float s = 0.f;
#pragma unroll
  for (int j = 0; j < 16; ++j) s += lin_w[o2 * 1024 + c * 16 + j];
  W2[o2 * 64 + c] = s;
}

__global__ void prep_A(const float* __restrict__ cell_w,
                       const float* __restrict__ cell_b,
                       const float* __restrict__ lin_b,
                       const float* __restrict__ W2,
                       float* __restrict__ A, float* __restrict__ Abias) {
  int tid = blockIdx.x * blockDim.x + threadIdx.x;  // 262144
  int go = tid >> 10;
  int c = (tid >> 4) & 63;
  int p = tid & 15;
  int y = p >> 2, x = p & 3;
  int kn = (go >= 128) ? 16 : 48;
  int xb = (go >= 128) ? 48 : 0;
  float a = 0.f;
  for (int k = 0; k < kn; ++k)
    for (int dy = 0; dy < 3; ++dy) {
      int yy = y + dy - 1;
      if (yy < 0 || yy > 3) continue;
      for (int dx = 0; dx < 3; ++dx) {
        int xx = x + dx - 1;
        if (xx < 0 || xx > 3) continue;
        a += cell_w[((go * 48 + k) * 3 + dy) * 3 + dx] *
             W2[((xb + k) * 16 + yy * 4 + xx) * 64 + c];
      }
    }
  A[(go * 64 + c) * 16 + p] = a;
  if (c == 0) {
    float bs = cell_b[go];
    for (int k = 0; k < kn; ++k)
      for (int dy = 0; dy < 3; ++dy) {
        int yy = y + dy - 1;
        if (yy < 0 || yy > 3) continue;
        for (int dx = 0; dx < 3; ++dx) {
          int xx = x + dx - 1;
          if (xx < 0 || xx > 3) continue;
          bs += cell_w[((go * 48 + k) * 3 + dy) * 3 + dx] *
                lin_b[(xb + k) * 16 + yy * 4 + xx];
        }
      }
    Abias[go * 16 + p] = bs;
  }
}

// A fp32 [go][c][p] -> 16x16x32 A-frags: Apk[go][kch][lane][8]
__global__ void pack_a16(const float* __restrict__ A, _Float16* __restrict__ Apk) {
  int tid = blockIdx.x * blockDim.x + threadIdx.x;  // 262144
  int j = tid & 7, lane = (tid >> 3) & 63, kch = (tid >> 9) & 1, go = tid >> 10;
  int p = lane & 15;
  int c = kch * 32 + (lane >> 4) * 8 + j;
  Apk[tid] = (_Float16)A[(go * 64 + c) * 16 + p];
}

// cell_w -> 32x32x16 conv A-frags: [f 2kch | o 3kch | g 3kch][(kch*9+tap)*4+m][lane][8]
__global__ void pack_wcv(const float* __restrict__ cell_w, _Float16* __restrict__ Wcv) {
  int tid = blockIdx.x * blockDim.x + threadIdx.x;  // 147456
  int j = tid & 7, lane = (tid >> 3) & 63, m = (tid >> 9) & 3, tmk = tid >> 11;
  int co = m * 32 + (lane & 31);
  int khi = (lane >> 5) * 8 + j;
  float v;
  if (tmk < 18) {
    int kch = tmk / 9, tap = tmk % 9;
    v = cell_w[((size_t)(128 + co) * 48 + 16 + kch * 16 + khi) * 9 + tap];
  } else if (tmk < 45) {
    int r = tmk - 18; int kch = r / 9, tap = r % 9;
    v = cell_w[((size_t)(256 + co) * 48 + kch * 16 + khi) * 9 + tap];
  } else {
    int r = tmk - 45; int kch = r / 9, tap = r % 9;
    v = cell_w[((size_t)(384 + co) * 48 + kch * 16 + khi) * 9 + tap];
  }
  Wcv[tid] = (_Float16)v;
}

__device__ __forceinline__ float sigm(float v) {
  return __fdividef(1.f, 1.f + __expf(-v));
}
__device__ __forceinline__ float tanh_fast(float v) {
  return 1.f - __fdividef(2.f, __expf(2.f * v) + 1.f);
}

// ---------------------------------------------------------------------------
// xgate: round-5 version verbatim (verified best: ~52 us/dispatch).
// ---------------------------------------------------------------------------
__global__ __launch_bounds__(256, 3) void xgate_kernel(
    const float* __restrict__ x, const _Float16* __restrict__ WeF,
    const float* __restrict__ be, const _Float16* __restrict__ Apk,
    const float* __restrict__ Abias, unsigned short* __restrict__ sixf, int tc) {
  __shared__ __align__(16) _Float16 x16[128 * 104];     // 26624 B
  __shared__ __align__(16) _Float16 enc_s[128 * 72];    // 18432 B
  __shared__ __align__(16) unsigned char Tt[4 * 2304];  // 9216 B, wave-private
  int tid = threadIdx.x, lane = tid & 63, w = tid >> 6;
  int gq = blockIdx.x >> 7, cq = blockIdx.x & 127;
  int n = lane & 15, kgrp = lane >> 4;

  {
    int r = tid >> 1, half = tid & 1;
    int b = cq * 16 + (r >> 3), t = tc * 8 + (r & 7);
    const float* rowp = x + ((size_t)b * 128 + t) * 84;
#pragma unroll
    for (int j = 0; j < 11; ++j) {
      int q = half + 2 * j;
      if (q < 21) {
        float4 v = *(const float4*)(rowp + q * 4);
        f16x4 h;
        h[0] = (_Float16)v.x; h[1] = (_Float16)v.y;
        h[2] = (_Float16)v.z; h[3] = (_Float16)v.w;
        *(f16x4*)(&x16[r * 104 + q * 4]) = h;
      }
    }
    for (int i = tid; i < 4096; i += 256) {
      int rr = i >> 5, k = i & 31;
      if (k < 20) x16[rr * 104 + 84 + k] = (_Float16)0.f;
    }
  }
  __syncthreads();

  for (int ct4 = 0; ct4 < 8; ++ct4) {
    f32x4 acc = *(const f32x4*)(be + w * 16 + kgrp * 4);
#pragma unroll
    for (int kch = 0; kch < 3; ++kch)
      acc = __builtin_amdgcn_mfma_f32_16x16x32_f16(
          *(const f16x8*)(WeF + ((w * 3 + kch) * 64 + lane) * 8),
          *(const f16x8*)(&x16[(ct4 * 16 + n) * 104 + kch * 32 + kgrp * 8]),
          acc, 0, 0, 0);
#pragma unroll
    for (int r = 0; r < 4; ++r)
      enc_s[(ct4 * 16 + n) * 72 + w * 16 + kgrp * 4 + r] =
          (_Float16)fmaxf(acc[r], 0.f);
  }
  __syncthreads();

  int slotB = gq >> 1;
  int chbase = (gq & 1) * 64 + w * 16;
  unsigned char* Tw = Tt + w * 2304;
  int fn = lane >> 2;
  for (int ct4 = 0; ct4 < 8; ++ct4) {
    int ccl = ct4 * 16 + n;
    int fb = cq * 16 + ct4 * 2 + (fn >> 3), ftr = fn & 7;
    size_t grow =
        (((size_t)fb * 8 + ftr) * 2 + slotB) * 2048 + (size_t)chbase * 16;
    for (int gb = 0; gb < 4; ++gb) {
#pragma unroll
      for (int gi = 0; gi < 4; ++gi) {
        int gol = gb * 4 + gi;
        int go = gq * 64 + w * 16 + gol;
        f32x4 acc = *(const f32x4*)(Abias + go * 16 + kgrp * 4);
        acc = __builtin_amdgcn_mfma_f32_16x16x32_f16(
            *(const f16x8*)(Apk + (size_t)go * 1024 + lane * 8),
            *(const f16x8*)(&enc_s[ccl * 72 + kgrp * 8]), acc, 0, 0, 0);
        acc = __builtin_amdgcn_mfma_f32_16x16x32_f16(
            *(const f16x8*)(Apk + (size_t)go * 1024 + 512 + lane * 8),
            *(const f16x8*)(&enc_s[ccl * 72 + 32 + kgrp * 8]), acc, 0, 0, 0);
        unsigned char* tdst = Tw + n * 144 + gi * 32 + kgrp * 8;
        if (gq < 2) {
#pragma unroll
          for (int rp = 0; rp < 2; ++rp) {
            unsigned lo = (unsigned)(sigm(acc[rp * 2]) * 65535.f + 0.5f);
            unsigned hi = (unsigned)(sigm(acc[rp * 2 + 1]) * 65535.f + 0.5f);
            *(unsigned*)(tdst + rp * 4) = lo | (hi << 16);
          }
        } else {
#pragma unroll
          for (int rp = 0; rp < 2; ++rp) {
            f16x2 pv = {(_Float16)acc[rp * 2], (_Float16)acc[rp * 2 + 1]};
            *(f16x2*)(tdst + rp * 4) = pv;
          }
        }
      }
      asm volatile("s_waitcnt lgkmcnt(0)" ::: "memory");
      __builtin_amdgcn_sched_barrier(0);
#pragma unroll
      for (int j = 0; j < 2; ++j) {
        int chunk = (lane & 3) + 4 * j;
        f16x8 v = *(const f16x8*)(Tw + fn * 144 + chunk * 16);
        *(f16x8*)(sixf + grow + (size_t)gb * 64 + (size_t)chunk * 8) = v;
      }
      asm volatile("s_waitcnt lgkmcnt(0)" ::: "memory");
      __builtin_amdgcn_sched_barrier(0);
    }
  }
}

// ---------------------------------------------------------------------------
// recur8: round-5 version verbatim (162-165 us, spill-free optimum).
// 8 steps, 256 blocks x 768 thr (12 waves). Wave = (gate f/o/g, m).
// Conv weights in VGPRs; h in LDS f16; G raw f16 preact in LDS (144-B rows);
// c fp32 in LDS [16p][1024cell]. sixf layout [b][t][slot][ch][p].
// DO NOT add live values anywhere in the t-loop (r3/r4/r9/r11 spills).
// LDS map: h_pad [8b][17q][128ch] @0 (36992) | c [16p][1024cell] @36992
//          (65536) | G 3x[128ch rows 144B][4bl][16p] f16 @102528 (55296)
//          total 157824
// ---------------------------------------------------------------------------
#define HPB 4624
#define HPQ 272
#define ZQ 4352
#define COFF 36992
#define GOFF 102528
#define GSZ 18432
#define LDSZ 157824

__device__ __forceinline__ void cell_update(
    unsigned char* lds, const unsigned short* __restrict__ sixf_b,
    _Float16* __restrict__ h16_b, int ch, int bl, int hf, int t,
    float cbo, float cbg, bool lastT) {
  int b = hf * 4 + bl;
  int cell = hf * 512 + ch * 4 + bl;
  const unsigned short* sp = sixf_b + ((size_t)b * 8 + t) * 4096 + ch * 16;
  u16x8 s0 = *(const u16x8*)(sp);
  u16x8 s1 = *(const u16x8*)(sp + 8);
  f16x8 x0 = *(const f16x8*)(sp + 2048);
  f16x8 x1 = *(const f16x8*)(sp + 2056);
  const _Float16* Gf = (const _Float16*)(lds + GOFF + 0 * GSZ + ch * 144 + bl * 32);
  const _Float16* Go = (const _Float16*)(lds + GOFF + 1 * GSZ + ch * 144 + bl * 32);
  const _Float16* Gg = (const _Float16*)(lds + GOFF + 2 * GSZ + ch * 144 + bl * 32);
  float* cp = (float*)(lds + COFF) + cell;
#pragma unroll
  for (int h8 = 0; h8 < 2; ++h8) {
    u16x8 s = h8 ? s1 : s0;
    f16x8 xv = h8 ? x1 : x0;
    f16x8 gfv = *(const f16x8*)(Gf + h8 * 8);
    f16x8 gov = *(const f16x8*)(Go + h8 * 8);
    f16x8 ggv = *(const f16x8*)(Gg + h8 * 8);
#pragma unroll
    for (int j = 0; j < 8; ++j) {
      int p = h8 * 8 + j;
      float si = (float)s[j] * (1.f / 65535.f);
      float xf = (float)xv[j];
      float cold = cp[p * 1024];
      float cv = sigm(xf + (float)gfv[j]) * cold +
                 si * tanh_fast(cbg + (float)ggv[j]);
      cp[p * 1024] = cv;
      float hn = sigm(cbo + (float)gov[j]) * tanh_fast(cv);
      *(_Float16*)(lds + b * HPB + p * HPQ + ch * 2) = (_Float16)hn;
      if (lastT) h16_b[((size_t)b * 16 + p) * 128 + ch] = (_Float16)hn;
    }
  }
}

template <int GATE>
__device__ __forceinline__ void role_loop(
    unsigned char* lds, const _Float16* __restrict__ Wg,
    const unsigned short* __restrict__ sixf_b,
    _Float16* __restrict__ h16_b, const float* __restrict__ cell_b,
    int m, int lane, int tid, const unsigned* tapbase, unsigned gwbase) {
  constexpr int NKCH = (GATE == 0) ? 2 : 3;
  constexpr unsigned CIOFF = (GATE == 0) ? 0u : (GATE == 1 ? 64u : 160u);
  f16x8 wr[NKCH * 9];
#pragma unroll
  for (int fi = 0; fi < NKCH * 9; ++fi)
    wr[fi] = *(const f16x8*)(Wg + (size_t)(fi * 4 + m) * 512 + (lane << 3));

  int idx = (GATE == 2) ? (tid - 256) : tid;
  int ch = idx >> 2, bl = idx & 3;
  constexpr bool own0 = (GATE != 2), own1 = (GATE != 1);
  float cbo = cell_b[256 + ch], cbg = cell_b[384 + ch];

  for (int t = 0; t < 8; ++t) {
#pragma unroll
    for (int hf = 0; hf < 2; ++hf) {
#pragma unroll
      for (int nt = 0; nt < 2; ++nt) {
        unsigned bofs = (unsigned)(hf * 4 + nt * 2) * HPB;
        f32x16 acc = {};
#pragma unroll
        for (int kch = 0; kch < NKCH; ++kch)
#pragma unroll
          for (int tap = 0; tap < 9; ++tap)
            acc = __builtin_amdgcn_mfma_f32_32x32x16_f16(
                wr[kch * 9 + tap],
                *(const f16x8*)(lds + tapbase[tap] + bofs + CIOFF +
                                (unsigned)kch * 32),
                acc, 0, 0, 0);
#pragma unroll
        for (int r = 0; r < 16; ++r) {
          unsigned co_l = (unsigned)((r & 3) + 8 * (r >> 2));
          *(_Float16*)(lds + gwbase + (unsigned)GATE * GSZ + co_l * 144u +
                       (unsigned)nt * 64u) = (_Float16)acc[r];
        }
      }
      __syncthreads();
      if (hf == 0) {
        if (own0) cell_update(lds, sixf_b, h16_b, ch, bl, 0, t, cbo, cbg, t == 7);
      } else {
        if (own1) cell_update(lds, sixf_b, h16_b, ch, bl, 1, t, cbo, cbg, t == 7);
      }
      __syncthreads();
    }
  }
}

__global__ __launch_bounds__(768, 3) void recur8_kernel(
    const unsigned short* __restrict__ sixf, const _Float16* __restrict__ Wcv,
    const float* __restrict__ cell_b, _Float16* __restrict__ h16,
    float* __restrict__ cstate) {
  __shared__ __align__(16) unsigned char lds[LDSZ];
  int tid = threadIdx.x, lane = tid & 63, w = tid >> 6;
  int gate = w >> 2, m = w & 3;

  _Float16* h16_b = h16 + (size_t)blockIdx.x * 16384;
  for (int i = tid; i < 16384; i += 768) {
    int bl8 = i >> 11, q = (i >> 7) & 15, chh = i & 127;
    *(_Float16*)(lds + bl8 * HPB + q * HPQ + chh * 2) = h16_b[i];
  }
  for (int i = tid; i < 1024; i += 768) {
    int bl8 = i >> 7, chh = i & 127;
    *(_Float16*)(lds + bl8 * HPB + ZQ + chh * 2) = (_Float16)0.f;
  }
  float* cl = (float*)(lds + COFF);
  float* cst_b = cstate + (size_t)blockIdx.x * 16384;
  for (int i = tid; i < 16384; i += 768) cl[i] = cst_b[i];

  int col = lane & 31, khalf = lane >> 5, b_lo = col >> 4, p_c = col & 15;
  int yc = p_c >> 2, xc = p_c & 3;
  unsigned tapbase[9];
#pragma unroll
  for (int dy = 0; dy < 3; ++dy)
#pragma unroll
    for (int dx = 0; dx < 3; ++dx) {
      int qy = yc + dy - 1, qx = xc + dx - 1;
      bool valid = (qy >= 0 && qy < 4 && qx >= 0 && qx < 4);
      tapbase[dy * 3 + dx] =
          (valid ? (unsigned)((qy * 4 + qx) * HPQ) : (unsigned)ZQ) +
          (unsigned)(b_lo * HPB + khalf * 16);
    }
  unsigned gwbase = (unsigned)GOFF + (unsigned)((m * 32 + khalf * 4) * 144) +
                    (unsigned)(b_lo * 32 + p_c * 2);
  __syncthreads();

  const unsigned short* sixf_b = sixf + (size_t)blockIdx.x * 262144;
  if (gate == 0)
    role_loop<0>(lds, Wcv, sixf_b, h16_b, cell_b, m, lane, tid, tapbase, gwbase);
  else if (gate == 1)
    role_loop<1>(lds, Wcv + 36864, sixf_b, h16_b, cell_b, m, lane, tid, tapbase, gwbase);
  else
    role_loop<2>(lds, Wcv + 92160, sixf_b, h16_b, cell_b, m, lane, tid, tapbase, gwbase);

  // role_loop ends with a trailing __syncthreads(): all c updates visible.
  for (int i = tid; i < 16384; i += 768) cst_b[i] = cl[i];
}

__global__ __launch_bounds__(128) void cls_kernel(
    const _Float16* __restrict__ h16, const float* __restrict__ w1,
    const float* __restrict__ b1, const float* __restrict__ w2,
    const float* __restrict__ b2, float* __restrict__ out) {
  __shared__ __align__(16) float feat[8 * 2064];
  __shared__ float hid[8 * 128];
  int b0 = blockIdx.x * 8;
  for (int i = threadIdx.x; i < 16384; i += 128) {
    int bl = i >> 11, r = i & 2047, p = r >> 7, chh = r & 127;
    feat[bl * 2064 + chh * 16 + p] = (float)h16[(size_t)b0 * 2048 + i];
  }
  __syncthreads();
  int ch = threadIdx.x;
  float acc[8];
#pragma unroll
  for (int b = 0; b < 8; ++b) acc[b] = b1[ch];
  const float4* wr = (const float4*)(w1 + (size_t)ch * 2048);
  for (int k4 = 0; k4 < 512; ++k4) {
    float4 wv = wr[k4];
#pragma unroll
    for (int b = 0; b < 8; ++b) {
      float4 f = *(const float4*)(&feat[b * 2064 + k4 * 4]);
      acc[b] += wv.x * f.x + wv.y * f.y + wv.z * f.z + wv.w * f.w;
    }
  }
#pragma unroll
  for (int b = 0; b < 8; ++b) hid[b * 128 + ch] = fmaxf(acc[b], 0.f);
  __syncthreads();
  if (threadIdx.x < 16) {
    int b = threadIdx.x >> 1, o = threadIdx.x & 1;
    float s = b2[o];
    for (int k = 0; k < 128; ++k) s += hid[b * 128 + k] * w2[o * 128 + k];
    out[(size_t)(b0 + b) * 2 + o] = s;
  }
}

extern "C" void kernel_launch(void* const* d_in, const int* in_sizes, int n_in,
                              void* d_out, int out_size, void* d_ws, size_t ws_size,
                              hipStream_t stream) {
  const float* x        = (const float*)d_in[0];
  const float* conv1d_w = (const float*)d_in[1];
  const float* conv1d_b = (const float*)d_in[2];
  const float* bn_gamma = (const float*)d_in[3];
  const float* bn_beta  = (const float*)d_in[4];
  const float* bn_mean  = (const float*)d_in[5];
  const float* bn_var   = (const float*)d_in[6];
  const float* lin_w    = (const float*)d_in[7];
  const float* lin_b    = (const float*)d_in[8];
  const float* cell_w   = (const float*)d_in[9];
  const float* cell_b   = (const float*)d_in[10];
  const float* cls1_w   = (const float*)d_in[11];
  const float* cls1_b   = (const float*)d_in[12];
  const float* cls2_w   = (const float*)d_in[13];
  const float* cls2_b   = (const float*)d_in[14];

  float* ws = (float*)d_ws;
  float* We    = ws + 0;
  float* be    = ws + 8192;
  float* W2    = ws + 12288;
  float* A     = ws + 81920;
  float* Abias = ws + 344064;
  _Float16* WeF = (_Float16*)(ws + 348160);
  _Float16* Apk = (_Float16*)(ws + 352256);
  _Float16* Wcv = (_Float16*)(ws + 483328);
  _Float16* h16 = (_Float16*)(ws + 557056);
  float* cstate = ws + 2654208;
  unsigned short* sixf = (unsigned short*)(ws + 6848512);
  float* out = (float*)d_out;

  prep_enc_w<<<21, 256, 0, stream>>>(conv1d_w, conv1d_b, bn_gamma, bn_beta,
                                     bn_mean, bn_var, We, be);
  prep_wef<<<24, 256, 0, stream>>>(We, WeF);
  prep_w2<<<256, 256, 0, stream>>>(lin_w, W2);
  prep_A<<<1024, 256, 0, stream>>>(cell_w, cell_b, lin_b, W2, A, Abias);
  pack_a16<<<1024, 256, 0, stream>>>(A, Apk);
  pack_wcv<<<576, 256, 0, stream>>>(cell_w, Wcv);
  hipMemsetAsync(h16, 0, 8388608, stream);
  hipMemsetAsync(cstate, 0, 16777216, stream);
  for (int tc = 0; tc < 16; ++tc) {
    xgate_kernel<<<512, 256, 0, stream>>>(x, WeF, be, Apk, Abias, sixf, tc);
    recur8_kernel<<<256, 768, 0, stream>>>(sixf, Wcv, cell_b, h16, cstate);
  }
  cls_kernel<<<256, 128, 0, stream>>>(h16, cls1_w, cls1_b, cls2_w, cls2_b, out);
}